// Round 1
// 928.875 us; speedup vs baseline: 1.0971x; 1.0971x over previous
//
#include <hip/hip_runtime.h>
#include <math.h>

#define T_NO   200
#define C_NO   63
#define E_NO   2000
#define I_NO   500
#define TD     50000
#define TPAD   50048
#define EPSF   1e-8f

typedef float f32x4 __attribute__((ext_vector_type(4)));
typedef short s16x8 __attribute__((ext_vector_type(8)));

// ws layout (float offsets)
#define WS_HE    0              // 63*200
#define WS_HI    12600          // 63*200
#define WS_HOBS  25200          // 63*401 -> 50463
#define WS_COSB  50464          // 13*200 -> 53064
#define WS_OBSB  53064          // 25*401 -> 63089
#define WS_BE    63104          // bf16 64*2048 (65536 floats) -> 128640
#define WS_BI    128640         // bf16 64*512  (16384 floats) -> 145024
#define WS_PE0   145024         // 3 E partials, 64*TPAD each
#define PBSZ     3203072
#define WS_PI    9754240        // 1 I partial
#define WS_L0T   12957312       // 63*TPAD -> 16110336 floats (~61.5 MB)

// padded LDS map for FIR: +4 words every 32 data words
#define PADW(w) ((w) + (((w) >> 5) << 2))

__device__ inline unsigned short f2bf(float x) {   // RNE fp32->bf16
    unsigned u = __float_as_uint(x);
    return (unsigned short)((u + 0x7FFFu + ((u >> 16) & 1u)) >> 16);
}
__device__ inline unsigned pack2(float lo, float hi) {
    return (unsigned)f2bf(lo) | ((unsigned)f2bf(hi) << 16);
}

// ---------------- K0: raised-cosine bases (double math ONCE per basis point) --
__global__ void basis_kernel(float* __restrict__ ws) {
    const double PI = 3.14159265358979323846;
    int idx = blockIdx.x * blockDim.x + threadIdx.x;
    int stride = gridDim.x * blockDim.x;
    for (int p = idx; p < 13 * 200; p += stride) {
        int i = p / 200, t = p - i * 200;
        double raw = 5.0 * log((double)t + 1.0 + 1e-8);
        double phi = 0.5 * PI * (double)i;
        float b = (raw >= phi - PI && raw <= phi + PI) ? (float)(0.5 * cos(raw - phi) + 0.5) : 0.f;
        ws[WS_COSB + p] = b;
    }
    for (int p = idx; p < 25 * 401; p += stride) {
        int j = p / 401, x = p - j * 401;
        int i = (j + 1) >> 1;
        double raw = 5.0 * log(fabs((double)(x - 200)) + 1.0 + 1e-8);
        double phi = 0.5 * PI * (double)i;
        float b = (raw >= phi - PI && raw <= phi + PI) ? (float)(0.5 * cos(raw - phi) + 0.5) : 0.f;
        if (j > 0) {
            if (j & 1) { if (x < 200) b = 0.f; }   // row 2i-1: keep x>=200
            else       { if (x > 200) b = 0.f; }   // row 2i:   keep x<=200
        }
        ws[WS_OBSB + p] = b;
    }
}

// ---------------- K1: weight filters + pre-convert B matrices to bf16 --------
__global__ void prep_kernel(const float* __restrict__ Wsyn, const float* __restrict__ Wobs,
                            const float* __restrict__ Ce, const float* __restrict__ Ci,
                            float* __restrict__ ws) {
    int idx = blockIdx.x * blockDim.x + threadIdx.x;
    int stride = gridDim.x * blockDim.x;
    for (int p = idx; p < 63 * 200; p += stride) {
        int c = p / 200, t = p - c * 200;
        float ae = 0.f, ai = 0.f;
        #pragma unroll
        for (int b = 0; b < 13; ++b) {
            float bv = ws[WS_COSB + b * 200 + t];
            ae += Wsyn[(c * 13 + b) * 2 + 0] * bv;
            ai += Wsyn[(c * 13 + b) * 2 + 1] * bv;
        }
        ws[WS_HE + p] = ae;
        ws[WS_HI + p] = ai;
    }
    for (int p = idx; p < 63 * 401; p += stride) {
        int c = p / 401, x = p - c * 401;
        float a = 0.f;
        #pragma unroll
        for (int j = 0; j < 25; ++j)
            a += Wobs[c * 25 + j] * ws[WS_OBSB + j * 401 + x];
        ws[WS_HOBS + p] = a;
    }
    unsigned short* Be = (unsigned short*)(ws + WS_BE);
    for (int p = idx; p < 64 * 2048; p += stride) {
        int c = p >> 11, k = p & 2047;
        float v = (c < 63 && k < E_NO) ? Ce[(size_t)(c + 1) * E_NO + k] : 0.f;
        Be[p] = f2bf(v);
    }
    unsigned short* Bi = (unsigned short*)(ws + WS_BI);
    for (int p = idx; p < 64 * 512; p += stride) {
        int c = p >> 9, k = p & 511;
        float v = (c < 63 && k < I_NO) ? Ci[(size_t)(c + 1) * I_NO + k] : 0.f;
        Bi[p] = f2bf(v);
    }
}

// ---------------- K2: bf16 MFMA GEMM, 128t x 64c tile, split-K partials ------
// grid (391, 4): y<3 -> E chunk y (K 672 each over 2016-pad); y==3 -> I.
// A/B global loads are flat-index COALESCED: one wave load instruction touches
// 8 cache lines (A) / 16 L2-resident lines (B) instead of 64.
#define LDA 40   // bf16 row stride in LDS (80 B: 16B-aligned, 2-way banks max)
__global__ __launch_bounds__(128, 4) void gemm_kernel(const float* __restrict__ S_e,
                                                      const float* __restrict__ S_i,
                                                      float* __restrict__ ws) {
    __shared__ unsigned int Asu[128 * 20];   // 128 rows x 40 bf16
    __shared__ unsigned int Bsu[64 * 20];

    const int y = blockIdx.y;
    const bool isE = (y < 3);
    const float* S = isE ? S_e : S_i;
    const unsigned short* Bm = (const unsigned short*)(ws + (isE ? WS_BE : WS_BI));
    const int K     = isE ? E_NO : I_NO;
    const int Kpad  = isE ? 2048 : 512;
    const int kb    = isE ? y * 672 : 0;
    const int nst   = isE ? 21 : 16;
    float* outp = ws + (isE ? (WS_PE0 + (size_t)y * PBSZ) : WS_PI);

    const int tid  = threadIdx.x;
    const int lane = tid & 63;
    const int w    = tid >> 6;            // wave 0..1
    const int t0   = blockIdx.x * 128;

    // Coalesced A staging: flat float4 index idx = g*128+tid over the
    // 128row x 32k fp32 tile. row = idx>>3, c4 = idx&7. Lanes 0..7 cover
    // one contiguous 128B row segment.
    const int rA  = tid >> 3;       // base row (g adds 16 per step)
    const int c4A = tid & 7;        // float4 within row
    // Coalesced B staging: idx = g*128+tid over 64col x 32k bf16 tile
    // (4 x uint4 per col). col = idx>>2, seg = idx&3.
    const int cB  = tid >> 2;       // base col (g adds 32)
    const int sB  = tid & 3;        // uint4 within col

    float4 av[8];   // A: 8 float4, rows rA, rA+16, ..., rA+112
    uint4  bv[2];   // B: 2 uint4

    auto pf = [&](int s) {
        const int kk = kb + 32 * s;
        const int kA = kk + 4 * c4A;
        #pragma unroll
        for (int g = 0; g < 8; ++g) {
            int t = t0 + rA + 16 * g;
            float4 v = {0.f, 0.f, 0.f, 0.f};
            if (t < TD && kA < K) v = *(const float4*)(S + (size_t)t * K + kA);
            av[g] = v;
        }
        #pragma unroll
        for (int g = 0; g < 2; ++g) {
            int col = cB + 32 * g;
            bv[g] = *(const uint4*)(Bm + (size_t)col * Kpad + kk + sB * 8);
        }
    };

    f32x4 acc[4][4] = {};   // [t-tile][c-tile], 16x16 each
    pf(0);
    for (int s = 0; s < nst; ++s) {
        __syncthreads();
        #pragma unroll
        for (int g = 0; g < 8; ++g) {
            int r = rA + 16 * g;
            uint2 w2 = {pack2(av[g].x, av[g].y), pack2(av[g].z, av[g].w)};
            *(uint2*)(Asu + r * 20 + c4A * 2) = w2;
        }
        #pragma unroll
        for (int g = 0; g < 2; ++g) {
            int col = cB + 32 * g;
            *(uint4*)(Bsu + col * 20 + sB * 4) = bv[g];
        }
        __syncthreads();
        if (s + 1 < nst) pf(s + 1);

        const unsigned short* As = (const unsigned short*)Asu;
        const unsigned short* Bs = (const unsigned short*)Bsu;
        const int klocal = (lane >> 4) * 8;            // quad*8
        s16x8 af[4], bf[4];
        #pragma unroll
        for (int ta = 0; ta < 4; ++ta) {
            int row = 64 * w + 16 * ta + (lane & 15);
            af[ta] = *(const s16x8*)(As + row * LDA + klocal);
        }
        #pragma unroll
        for (int cb = 0; cb < 4; ++cb) {
            int col = 16 * cb + (lane & 15);
            bf[cb] = *(const s16x8*)(Bs + col * LDA + klocal);
        }
        #pragma unroll
        for (int ta = 0; ta < 4; ++ta)
            #pragma unroll
            for (int cb = 0; cb < 4; ++cb)
                acc[ta][cb] = __builtin_amdgcn_mfma_f32_16x16x32_bf16(af[ta], bf[cb], acc[ta][cb], 0, 0, 0);
    }

    // epilogue: C/D layout col=lane&15, row=4*(lane>>4)+reg  (m89-verified)
    const int cl = lane & 15, rq = 4 * (lane >> 4);
    #pragma unroll
    for (int ta = 0; ta < 4; ++ta)
        #pragma unroll
        for (int cb = 0; cb < 4; ++cb) {
            int c = 16 * cb + cl;
            float* dst = outp + (size_t)c * TPAD + t0 + 64 * w + 16 * ta + rq;
            f32x4 v = acc[ta][cb];
            *(float4*)dst = make_float4(v.x, v.y, v.z, v.w);
        }
}

// ---------------- K3: FIR (sums 3 E partials + 1 I partial) -------------------
__device__ inline float4 ldg4(const float* s, int m) {
    return *(const float4*)(s + 4 * m + ((m >> 3) << 2));
}

__global__ __launch_bounds__(256) void fir_kernel(const float* __restrict__ pE0,
                                                  const float* __restrict__ pE1,
                                                  const float* __restrict__ pE2,
                                                  const float* __restrict__ pI0,
                                                  const float* __restrict__ Z,
                                                  const float* __restrict__ he,
                                                  const float* __restrict__ hi,
                                                  const float* __restrict__ ho,
                                                  const float* __restrict__ Theta,
                                                  float* __restrict__ L0T) {
    __shared__ __align__(16) float sE[1392];
    __shared__ __align__(16) float sI[1392];
    __shared__ __align__(16) float zs[1616];
    __shared__ __align__(16) float heS[200];
    __shared__ __align__(16) float hiS[200];
    __shared__ __align__(16) float hoS[404];

    const int c   = blockIdx.y;
    const int t0  = blockIdx.x * 1024;
    const int tid = threadIdx.x;
    const int base = t0 - 203;

    for (int w = tid; w < 1228; w += 256) {
        int t = base + w;
        bool ok = (t >= 0 && t < TD);
        size_t idx = (size_t)c * TPAD + t;
        float ve = 0.f, vi = 0.f;
        if (ok) {
            ve = pE0[idx] + pE1[idx] + pE2[idx];
            vi = pI0[idx];
        }
        sE[PADW(w)] = ve;
        sI[PADW(w)] = vi;
    }
    for (int w = tid; w < 1428; w += 256) {
        int t = base + w;
        zs[PADW(w)] = (t >= 0 && t < TD) ? Z[t] : 0.f;
    }
    for (int d = tid; d < 200; d += 256) { heS[d] = he[c * 200 + d]; hiS[d] = hi[c * 200 + d]; }
    for (int d = tid; d < 401; d += 256) hoS[d] = ho[c * 401 + d];
    __syncthreads();

    const float th = Theta[c];
    float acc[4] = {th, th, th, th};

    {
        float4 eLo = ldg4(sE, tid + 50), eHi = ldg4(sE, tid + 51);
        float4 iLo = ldg4(sI, tid + 50), iHi = ldg4(sI, tid + 51);
        for (int dg = 0; dg < 50; ++dg) {
            const float4 h_e = *(const float4*)(heS + 4 * dg);
            const float4 h_i = *(const float4*)(hiS + 4 * dg);
            const float ew[8] = {eLo.x, eLo.y, eLo.z, eLo.w, eHi.x, eHi.y, eHi.z, eHi.w};
            const float iw[8] = {iLo.x, iLo.y, iLo.z, iLo.w, iHi.x, iHi.y, iHi.z, iHi.w};
            const float heq[4] = {h_e.x, h_e.y, h_e.z, h_e.w};
            const float hiq[4] = {h_i.x, h_i.y, h_i.z, h_i.w};
            #pragma unroll
            for (int q = 0; q < 4; ++q)
                #pragma unroll
                for (int r = 0; r < 4; ++r) {
                    const int o = 3 + r - q;
                    acc[r] += ew[o] * heq[q] + iw[o] * hiq[q];
                }
            eHi = eLo; iHi = iLo;
            if (dg < 49) { eLo = ldg4(sE, tid + 49 - dg); iLo = ldg4(sI, tid + 49 - dg); }
        }
    }
    {
        float4 zLo = ldg4(zs, tid + 100), zHi = ldg4(zs, tid + 101);
        for (int dg = 0; dg < 100; ++dg) {
            const float4 h_o = *(const float4*)(hoS + 4 * dg);
            const float zw[8] = {zLo.x, zLo.y, zLo.z, zLo.w, zHi.x, zHi.y, zHi.z, zHi.w};
            const float hoq[4] = {h_o.x, h_o.y, h_o.z, h_o.w};
            #pragma unroll
            for (int q = 0; q < 4; ++q)
                #pragma unroll
                for (int r = 0; r < 4; ++r) {
                    const int o = 3 + r - q;
                    acc[r] += zw[o] * hoq[q];
                }
            zHi = zLo;
            if (dg < 99) zLo = ldg4(zs, tid + 99 - dg);
        }
        const float h400 = hoS[400];
        #pragma unroll
        for (int r = 0; r < 4; ++r) {
            int w = 4 * tid + 3 + r;
            acc[r] += zs[PADW(w)] * h400;
        }
    }

    const int tb = t0 + 4 * tid;
    if (tb + 3 < TD) {
        float4 v = {acc[0], acc[1], acc[2], acc[3]};
        *(float4*)(L0T + (size_t)c * TPAD + tb) = v;
    } else {
        #pragma unroll
        for (int r = 0; r < 4; ++r)
            if (tb + r < TD) L0T[(size_t)c * TPAD + tb + r] = acc[r];
    }
}

// ---------------- K4: transpose + Gumbel softmax + sigmoid --------------------
__global__ __launch_bounds__(256) void out_kernel(const float* __restrict__ L0T,
                                                  const float* __restrict__ u,
                                                  const float* __restrict__ temp_p,
                                                  float* __restrict__ out) {
    __shared__ float tile[63 * 65];
    const int t0 = blockIdx.x * 64;
    const int tid = threadIdx.x;

    for (int l = tid; l < 1008; l += 256) {
        int cc = l >> 4;
        int jg = (l & 15) << 2;
        float4 v = *(const float4*)(L0T + (size_t)cc * TPAD + t0 + jg);
        tile[cc * 65 + jg + 0] = v.x;
        tile[cc * 65 + jg + 1] = v.y;
        tile[cc * 65 + jg + 2] = v.z;
        tile[cc * 65 + jg + 3] = v.w;
    }
    __syncthreads();

    const float inv_temp = 1.f / (*temp_p);
    for (int l = tid; l < 4032; l += 256) {
        int tl = l / 63;
        int cc = l - tl * 63;
        int t = t0 + tl;
        if (t < TD) {
            float L0 = tile[cc * 65 + tl];
            float2 uv = *(const float2*)(u + 2 * ((size_t)t * 63 + cc));
            float g0 = -logf(-logf(uv.x + EPSF) + EPSF);
            float g1 = -logf(-logf(uv.y + EPSF) + EPSF);
            float zh = 1.f / (1.f + expf(-((L0 + g0 - g1) * inv_temp)));
            float sg = 1.f / (1.f + expf(-L0));
            out[(size_t)t * 63 + cc] = zh;
            out[3150000 + (size_t)t * 63 + cc] = sg;
        }
    }
}

extern "C" void kernel_launch(void* const* d_in, const int* in_sizes, int n_in,
                              void* d_out, int out_size, void* d_ws, size_t ws_size,
                              hipStream_t stream) {
    (void)in_sizes; (void)n_in; (void)out_size; (void)ws_size;
    const float* S_e   = (const float*)d_in[0];
    const float* S_i   = (const float*)d_in[1];
    const float* Z     = (const float*)d_in[2];
    const float* temp  = (const float*)d_in[3];
    const float* u     = (const float*)d_in[4];
    const float* Ce    = (const float*)d_in[5];
    const float* Ci    = (const float*)d_in[6];
    const float* Wsyn  = (const float*)d_in[7];
    const float* Wobs  = (const float*)d_in[8];
    const float* Theta = (const float*)d_in[9];
    float* out = (float*)d_out;
    float* ws  = (float*)d_ws;

    hipLaunchKernelGGL(basis_kernel, dim3(50), dim3(256), 0, stream, ws);
    hipLaunchKernelGGL(prep_kernel, dim3(256), dim3(256), 0, stream, Wsyn, Wobs, Ce, Ci, ws);
    hipLaunchKernelGGL(gemm_kernel, dim3(391, 4), dim3(128), 0, stream, S_e, S_i, ws);
    hipLaunchKernelGGL(fir_kernel, dim3(49, 63), dim3(256), 0, stream,
                       ws + WS_PE0, ws + WS_PE0 + PBSZ, ws + WS_PE0 + 2 * (size_t)PBSZ,
                       ws + WS_PI, Z,
                       ws + WS_HE, ws + WS_HI, ws + WS_HOBS, Theta, ws + WS_L0T);
    hipLaunchKernelGGL(out_kernel, dim3(782), dim3(256), 0, stream, ws + WS_L0T, u, temp, out);
}

// Round 2
// 909.638 us; speedup vs baseline: 1.1203x; 1.0211x over previous
//
#include <hip/hip_runtime.h>
#include <math.h>

#define T_NO   200
#define C_NO   63
#define E_NO   2000
#define I_NO   500
#define TD     50000
#define TPAD   50048
#define EPSF   1e-8f

typedef float f32x4 __attribute__((ext_vector_type(4)));
typedef short s16x8 __attribute__((ext_vector_type(8)));

// ws layout (float offsets)
#define WS_HE    0              // 63*200
#define WS_HI    12600          // 63*200
#define WS_HOBS  25200          // 63*401 -> 50463
#define WS_COSB  50464          // 13*200 -> 53064
#define WS_OBSB  53064          // 25*401 -> 63089
#define WS_BE    63104          // bf16 64*2048 (65536 floats) -> 128640
#define WS_BI    128640         // bf16 64*512  (16384 floats) -> 145024
#define WS_PE0   145024         // 3 E partials, 64*TPAD each
#define PBSZ     3203072
#define WS_PI    9754240        // 1 I partial
#define WS_L0T   12957312       // 63*TPAD -> 16110336 floats (~61.5 MB)

// padded LDS map for FIR: +4 words every 32 data words
#define PADW(w) ((w) + (((w) >> 5) << 2))

__device__ inline unsigned short f2bf(float x) {   // RNE fp32->bf16
    unsigned u = __float_as_uint(x);
    return (unsigned short)((u + 0x7FFFu + ((u >> 16) & 1u)) >> 16);
}
__device__ inline unsigned pack2(float lo, float hi) {
    return (unsigned)f2bf(lo) | ((unsigned)f2bf(hi) << 16);
}

// ---------------- K0: raised-cosine bases (double math ONCE per basis point) --
__global__ void basis_kernel(float* __restrict__ ws) {
    const double PI = 3.14159265358979323846;
    int idx = blockIdx.x * blockDim.x + threadIdx.x;
    int stride = gridDim.x * blockDim.x;
    for (int p = idx; p < 13 * 200; p += stride) {
        int i = p / 200, t = p - i * 200;
        double raw = 5.0 * log((double)t + 1.0 + 1e-8);
        double phi = 0.5 * PI * (double)i;
        float b = (raw >= phi - PI && raw <= phi + PI) ? (float)(0.5 * cos(raw - phi) + 0.5) : 0.f;
        ws[WS_COSB + p] = b;
    }
    for (int p = idx; p < 25 * 401; p += stride) {
        int j = p / 401, x = p - j * 401;
        int i = (j + 1) >> 1;
        double raw = 5.0 * log(fabs((double)(x - 200)) + 1.0 + 1e-8);
        double phi = 0.5 * PI * (double)i;
        float b = (raw >= phi - PI && raw <= phi + PI) ? (float)(0.5 * cos(raw - phi) + 0.5) : 0.f;
        if (j > 0) {
            if (j & 1) { if (x < 200) b = 0.f; }   // row 2i-1: keep x>=200
            else       { if (x > 200) b = 0.f; }   // row 2i:   keep x<=200
        }
        ws[WS_OBSB + p] = b;
    }
}

// ---------------- K1: weight filters + pre-convert B matrices to bf16 --------
__global__ void prep_kernel(const float* __restrict__ Wsyn, const float* __restrict__ Wobs,
                            const float* __restrict__ Ce, const float* __restrict__ Ci,
                            float* __restrict__ ws) {
    int idx = blockIdx.x * blockDim.x + threadIdx.x;
    int stride = gridDim.x * blockDim.x;
    for (int p = idx; p < 63 * 200; p += stride) {
        int c = p / 200, t = p - c * 200;
        float ae = 0.f, ai = 0.f;
        #pragma unroll
        for (int b = 0; b < 13; ++b) {
            float bv = ws[WS_COSB + b * 200 + t];
            ae += Wsyn[(c * 13 + b) * 2 + 0] * bv;
            ai += Wsyn[(c * 13 + b) * 2 + 1] * bv;
        }
        ws[WS_HE + p] = ae;
        ws[WS_HI + p] = ai;
    }
    for (int p = idx; p < 63 * 401; p += stride) {
        int c = p / 401, x = p - c * 401;
        float a = 0.f;
        #pragma unroll
        for (int j = 0; j < 25; ++j)
            a += Wobs[c * 25 + j] * ws[WS_OBSB + j * 401 + x];
        ws[WS_HOBS + p] = a;
    }
    unsigned short* Be = (unsigned short*)(ws + WS_BE);
    for (int p = idx; p < 64 * 2048; p += stride) {
        int c = p >> 11, k = p & 2047;
        float v = (c < 63 && k < E_NO) ? Ce[(size_t)(c + 1) * E_NO + k] : 0.f;
        Be[p] = f2bf(v);
    }
    unsigned short* Bi = (unsigned short*)(ws + WS_BI);
    for (int p = idx; p < 64 * 512; p += stride) {
        int c = p >> 9, k = p & 511;
        float v = (c < 63 && k < I_NO) ? Ci[(size_t)(c + 1) * I_NO + k] : 0.f;
        Bi[p] = f2bf(v);
    }
}

// ---------------- K2: bf16 MFMA GEMM, 64t x 64c tile, split-K partials -------
// grid (782, 4): y<3 -> E chunk y (K 672 each over 2016-pad); y==3 -> I.
// 64-row tile doubles the block count vs the 128-row version: 3128 blocks =
// 12.2 blocks/CU (was 6.1) -> TLP actually hides the per-step HBM latency.
// A/B global loads flat-index coalesced (8 lines/wave-instr for A).
#define LDA 40   // bf16 row stride in LDS (80 B: 16B-aligned, 2-way banks max)
__global__ __launch_bounds__(128, 4) void gemm_kernel(const float* __restrict__ S_e,
                                                      const float* __restrict__ S_i,
                                                      float* __restrict__ ws) {
    __shared__ unsigned int Asu[64 * 20];   // 64 rows x 40 bf16
    __shared__ unsigned int Bsu[64 * 20];

    const int y = blockIdx.y;
    const bool isE = (y < 3);
    const float* S = isE ? S_e : S_i;
    const unsigned short* Bm = (const unsigned short*)(ws + (isE ? WS_BE : WS_BI));
    const int K     = isE ? E_NO : I_NO;
    const int Kpad  = isE ? 2048 : 512;
    const int kb    = isE ? y * 672 : 0;
    const int nst   = isE ? 21 : 16;
    float* outp = ws + (isE ? (WS_PE0 + (size_t)y * PBSZ) : WS_PI);

    const int tid  = threadIdx.x;
    const int lane = tid & 63;
    const int w    = tid >> 6;            // wave 0..1
    const int t0   = blockIdx.x * 64;

    // Coalesced A staging: flat float4 index over the 64row x 32k fp32 tile.
    // row = idx>>3, c4 = idx&7. Lanes 0..7 cover one contiguous 128B row seg.
    const int rA  = tid >> 3;       // base row (g adds 16 per step, g=0..3)
    const int c4A = tid & 7;        // float4 within row
    // Coalesced B staging: flat uint4 index over 64col x 32k bf16 tile.
    const int cB  = tid >> 2;       // base col (g adds 32, g=0..1)
    const int sB  = tid & 3;        // uint4 within col

    float4 av[4];   // A: rows rA, rA+16, rA+32, rA+48
    uint4  bv[2];   // B: cols cB, cB+32

    auto pf = [&](int s) {
        const int kk = kb + 32 * s;
        const int kA = kk + 4 * c4A;
        #pragma unroll
        for (int g = 0; g < 4; ++g) {
            int t = t0 + rA + 16 * g;
            float4 v = {0.f, 0.f, 0.f, 0.f};
            if (t < TD && kA < K) v = *(const float4*)(S + (size_t)t * K + kA);
            av[g] = v;
        }
        #pragma unroll
        for (int g = 0; g < 2; ++g) {
            int col = cB + 32 * g;
            bv[g] = *(const uint4*)(Bm + (size_t)col * Kpad + kk + sB * 8);
        }
    };

    f32x4 acc[2][4] = {};   // [t-tile][c-tile], 16x16 each
    pf(0);
    for (int s = 0; s < nst; ++s) {
        __syncthreads();
        #pragma unroll
        for (int g = 0; g < 4; ++g) {
            int r = rA + 16 * g;
            uint2 w2 = {pack2(av[g].x, av[g].y), pack2(av[g].z, av[g].w)};
            *(uint2*)(Asu + r * 20 + c4A * 2) = w2;
        }
        #pragma unroll
        for (int g = 0; g < 2; ++g) {
            int col = cB + 32 * g;
            *(uint4*)(Bsu + col * 20 + sB * 4) = bv[g];
        }
        __syncthreads();
        if (s + 1 < nst) pf(s + 1);

        const unsigned short* As = (const unsigned short*)Asu;
        const unsigned short* Bs = (const unsigned short*)Bsu;
        const int klocal = (lane >> 4) * 8;            // quad*8
        s16x8 af[2], bf[4];
        #pragma unroll
        for (int ta = 0; ta < 2; ++ta) {
            int row = 32 * w + 16 * ta + (lane & 15);
            af[ta] = *(const s16x8*)(As + row * LDA + klocal);
        }
        #pragma unroll
        for (int cb = 0; cb < 4; ++cb) {
            int col = 16 * cb + (lane & 15);
            bf[cb] = *(const s16x8*)(Bs + col * LDA + klocal);
        }
        #pragma unroll
        for (int ta = 0; ta < 2; ++ta)
            #pragma unroll
            for (int cb = 0; cb < 4; ++cb)
                acc[ta][cb] = __builtin_amdgcn_mfma_f32_16x16x32_bf16(af[ta], bf[cb], acc[ta][cb], 0, 0, 0);
    }

    // epilogue: C/D layout col=lane&15, row=4*(lane>>4)+reg  (m89-verified)
    const int cl = lane & 15, rq = 4 * (lane >> 4);
    #pragma unroll
    for (int ta = 0; ta < 2; ++ta)
        #pragma unroll
        for (int cb = 0; cb < 4; ++cb) {
            int c = 16 * cb + cl;
            float* dst = outp + (size_t)c * TPAD + t0 + 32 * w + 16 * ta + rq;
            f32x4 v = acc[ta][cb];
            *(float4*)dst = make_float4(v.x, v.y, v.z, v.w);
        }
}

// ---------------- K3: FIR (sums 3 E partials + 1 I partial) -------------------
__device__ inline float4 ldg4(const float* s, int m) {
    return *(const float4*)(s + 4 * m + ((m >> 3) << 2));
}

__global__ __launch_bounds__(256) void fir_kernel(const float* __restrict__ pE0,
                                                  const float* __restrict__ pE1,
                                                  const float* __restrict__ pE2,
                                                  const float* __restrict__ pI0,
                                                  const float* __restrict__ Z,
                                                  const float* __restrict__ he,
                                                  const float* __restrict__ hi,
                                                  const float* __restrict__ ho,
                                                  const float* __restrict__ Theta,
                                                  float* __restrict__ L0T) {
    __shared__ __align__(16) float sE[1392];
    __shared__ __align__(16) float sI[1392];
    __shared__ __align__(16) float zs[1616];
    __shared__ __align__(16) float heS[200];
    __shared__ __align__(16) float hiS[200];
    __shared__ __align__(16) float hoS[404];

    const int c   = blockIdx.y;
    const int t0  = blockIdx.x * 1024;
    const int tid = threadIdx.x;
    const int base = t0 - 203;

    for (int w = tid; w < 1228; w += 256) {
        int t = base + w;
        bool ok = (t >= 0 && t < TD);
        size_t idx = (size_t)c * TPAD + t;
        float ve = 0.f, vi = 0.f;
        if (ok) {
            ve = pE0[idx] + pE1[idx] + pE2[idx];
            vi = pI0[idx];
        }
        sE[PADW(w)] = ve;
        sI[PADW(w)] = vi;
    }
    for (int w = tid; w < 1428; w += 256) {
        int t = base + w;
        zs[PADW(w)] = (t >= 0 && t < TD) ? Z[t] : 0.f;
    }
    for (int d = tid; d < 200; d += 256) { heS[d] = he[c * 200 + d]; hiS[d] = hi[c * 200 + d]; }
    for (int d = tid; d < 401; d += 256) hoS[d] = ho[c * 401 + d];
    __syncthreads();

    const float th = Theta[c];
    float acc[4] = {th, th, th, th};

    {
        float4 eLo = ldg4(sE, tid + 50), eHi = ldg4(sE, tid + 51);
        float4 iLo = ldg4(sI, tid + 50), iHi = ldg4(sI, tid + 51);
        for (int dg = 0; dg < 50; ++dg) {
            const float4 h_e = *(const float4*)(heS + 4 * dg);
            const float4 h_i = *(const float4*)(hiS + 4 * dg);
            const float ew[8] = {eLo.x, eLo.y, eLo.z, eLo.w, eHi.x, eHi.y, eHi.z, eHi.w};
            const float iw[8] = {iLo.x, iLo.y, iLo.z, iLo.w, iHi.x, iHi.y, iHi.z, iHi.w};
            const float heq[4] = {h_e.x, h_e.y, h_e.z, h_e.w};
            const float hiq[4] = {h_i.x, h_i.y, h_i.z, h_i.w};
            #pragma unroll
            for (int q = 0; q < 4; ++q)
                #pragma unroll
                for (int r = 0; r < 4; ++r) {
                    const int o = 3 + r - q;
                    acc[r] += ew[o] * heq[q] + iw[o] * hiq[q];
                }
            eHi = eLo; iHi = iLo;
            if (dg < 49) { eLo = ldg4(sE, tid + 49 - dg); iLo = ldg4(sI, tid + 49 - dg); }
        }
    }
    {
        float4 zLo = ldg4(zs, tid + 100), zHi = ldg4(zs, tid + 101);
        for (int dg = 0; dg < 100; ++dg) {
            const float4 h_o = *(const float4*)(hoS + 4 * dg);
            const float zw[8] = {zLo.x, zLo.y, zLo.z, zLo.w, zHi.x, zHi.y, zHi.z, zHi.w};
            const float hoq[4] = {h_o.x, h_o.y, h_o.z, h_o.w};
            #pragma unroll
            for (int q = 0; q < 4; ++q)
                #pragma unroll
                for (int r = 0; r < 4; ++r) {
                    const int o = 3 + r - q;
                    acc[r] += zw[o] * hoq[q];
                }
            zHi = zLo;
            if (dg < 99) zLo = ldg4(zs, tid + 99 - dg);
        }
        const float h400 = hoS[400];
        #pragma unroll
        for (int r = 0; r < 4; ++r) {
            int w = 4 * tid + 3 + r;
            acc[r] += zs[PADW(w)] * h400;
        }
    }

    const int tb = t0 + 4 * tid;
    if (tb + 3 < TD) {
        float4 v = {acc[0], acc[1], acc[2], acc[3]};
        *(float4*)(L0T + (size_t)c * TPAD + tb) = v;
    } else {
        #pragma unroll
        for (int r = 0; r < 4; ++r)
            if (tb + r < TD) L0T[(size_t)c * TPAD + tb + r] = acc[r];
    }
}

// ---------------- K4: transpose + Gumbel softmax + sigmoid --------------------
__global__ __launch_bounds__(256) void out_kernel(const float* __restrict__ L0T,
                                                  const float* __restrict__ u,
                                                  const float* __restrict__ temp_p,
                                                  float* __restrict__ out) {
    __shared__ float tile[63 * 65];
    const int t0 = blockIdx.x * 64;
    const int tid = threadIdx.x;

    for (int l = tid; l < 1008; l += 256) {
        int cc = l >> 4;
        int jg = (l & 15) << 2;
        float4 v = *(const float4*)(L0T + (size_t)cc * TPAD + t0 + jg);
        tile[cc * 65 + jg + 0] = v.x;
        tile[cc * 65 + jg + 1] = v.y;
        tile[cc * 65 + jg + 2] = v.z;
        tile[cc * 65 + jg + 3] = v.w;
    }
    __syncthreads();

    const float inv_temp = 1.f / (*temp_p);
    for (int l = tid; l < 4032; l += 256) {
        int tl = l / 63;
        int cc = l - tl * 63;
        int t = t0 + tl;
        if (t < TD) {
            float L0 = tile[cc * 65 + tl];
            float2 uv = *(const float2*)(u + 2 * ((size_t)t * 63 + cc));
            float g0 = -logf(-logf(uv.x + EPSF) + EPSF);
            float g1 = -logf(-logf(uv.y + EPSF) + EPSF);
            float zh = 1.f / (1.f + expf(-((L0 + g0 - g1) * inv_temp)));
            float sg = 1.f / (1.f + expf(-L0));
            out[(size_t)t * 63 + cc] = zh;
            out[3150000 + (size_t)t * 63 + cc] = sg;
        }
    }
}

extern "C" void kernel_launch(void* const* d_in, const int* in_sizes, int n_in,
                              void* d_out, int out_size, void* d_ws, size_t ws_size,
                              hipStream_t stream) {
    (void)in_sizes; (void)n_in; (void)out_size; (void)ws_size;
    const float* S_e   = (const float*)d_in[0];
    const float* S_i   = (const float*)d_in[1];
    const float* Z     = (const float*)d_in[2];
    const float* temp  = (const float*)d_in[3];
    const float* u     = (const float*)d_in[4];
    const float* Ce    = (const float*)d_in[5];
    const float* Ci    = (const float*)d_in[6];
    const float* Wsyn  = (const float*)d_in[7];
    const float* Wobs  = (const float*)d_in[8];
    const float* Theta = (const float*)d_in[9];
    float* out = (float*)d_out;
    float* ws  = (float*)d_ws;

    hipLaunchKernelGGL(basis_kernel, dim3(50), dim3(256), 0, stream, ws);
    hipLaunchKernelGGL(prep_kernel, dim3(256), dim3(256), 0, stream, Wsyn, Wobs, Ce, Ci, ws);
    hipLaunchKernelGGL(gemm_kernel, dim3(782, 4), dim3(128), 0, stream, S_e, S_i, ws);
    hipLaunchKernelGGL(fir_kernel, dim3(49, 63), dim3(256), 0, stream,
                       ws + WS_PE0, ws + WS_PE0 + PBSZ, ws + WS_PE0 + 2 * (size_t)PBSZ,
                       ws + WS_PI, Z,
                       ws + WS_HE, ws + WS_HI, ws + WS_HOBS, Theta, ws + WS_L0T);
    hipLaunchKernelGGL(out_kernel, dim3(782), dim3(256), 0, stream, ws + WS_L0T, u, temp, out);
}

// Round 3
// 900.272 us; speedup vs baseline: 1.1320x; 1.0104x over previous
//
#include <hip/hip_runtime.h>
#include <math.h>

#define T_NO   200
#define C_NO   63
#define E_NO   2000
#define I_NO   500
#define TD     50000
#define TPAD   50048
#define EPSF   1e-8f

typedef float f32x4 __attribute__((ext_vector_type(4)));
typedef short s16x8 __attribute__((ext_vector_type(8)));

// ws layout (float offsets)
#define WS_HE    0              // 63*200
#define WS_HI    12600          // 63*200
#define WS_HOBS  25200          // 63*401 -> 50463
#define WS_COSB  50464          // 13*200 -> 53064
#define WS_OBSB  53064          // 25*401 -> 63089
#define WS_BE    63104          // bf16 64*2048 (65536 floats) -> 128640
#define WS_BI    128640         // bf16 64*512  (16384 floats) -> 145024
#define WS_PE0   145024         // 3 E partials, 64*TPAD each
#define PBSZ     3203072
#define WS_PI    9754240        // 1 I partial
#define WS_L0T   12957312       // 63*TPAD -> 16110336 floats (~61.5 MB)

// padded LDS map for FIR: +4 words every 32 data words
#define PADW(w) ((w) + (((w) >> 5) << 2))

__device__ inline unsigned short f2bf(float x) {   // RNE fp32->bf16
    unsigned u = __float_as_uint(x);
    return (unsigned short)((u + 0x7FFFu + ((u >> 16) & 1u)) >> 16);
}
__device__ inline unsigned pack2(float lo, float hi) {
    return (unsigned)f2bf(lo) | ((unsigned)f2bf(hi) << 16);
}

// ---------------- K0: raised-cosine bases (double math ONCE per basis point) --
__global__ void basis_kernel(float* __restrict__ ws) {
    const double PI = 3.14159265358979323846;
    int idx = blockIdx.x * blockDim.x + threadIdx.x;
    int stride = gridDim.x * blockDim.x;
    for (int p = idx; p < 13 * 200; p += stride) {
        int i = p / 200, t = p - i * 200;
        double raw = 5.0 * log((double)t + 1.0 + 1e-8);
        double phi = 0.5 * PI * (double)i;
        float b = (raw >= phi - PI && raw <= phi + PI) ? (float)(0.5 * cos(raw - phi) + 0.5) : 0.f;
        ws[WS_COSB + p] = b;
    }
    for (int p = idx; p < 25 * 401; p += stride) {
        int j = p / 401, x = p - j * 401;
        int i = (j + 1) >> 1;
        double raw = 5.0 * log(fabs((double)(x - 200)) + 1.0 + 1e-8);
        double phi = 0.5 * PI * (double)i;
        float b = (raw >= phi - PI && raw <= phi + PI) ? (float)(0.5 * cos(raw - phi) + 0.5) : 0.f;
        if (j > 0) {
            if (j & 1) { if (x < 200) b = 0.f; }   // row 2i-1: keep x>=200
            else       { if (x > 200) b = 0.f; }   // row 2i:   keep x<=200
        }
        ws[WS_OBSB + p] = b;
    }
}

// ---------------- K1: weight filters + pre-convert B matrices to bf16 --------
__global__ void prep_kernel(const float* __restrict__ Wsyn, const float* __restrict__ Wobs,
                            const float* __restrict__ Ce, const float* __restrict__ Ci,
                            float* __restrict__ ws) {
    int idx = blockIdx.x * blockDim.x + threadIdx.x;
    int stride = gridDim.x * blockDim.x;
    for (int p = idx; p < 63 * 200; p += stride) {
        int c = p / 200, t = p - c * 200;
        float ae = 0.f, ai = 0.f;
        #pragma unroll
        for (int b = 0; b < 13; ++b) {
            float bv = ws[WS_COSB + b * 200 + t];
            ae += Wsyn[(c * 13 + b) * 2 + 0] * bv;
            ai += Wsyn[(c * 13 + b) * 2 + 1] * bv;
        }
        ws[WS_HE + p] = ae;
        ws[WS_HI + p] = ai;
    }
    for (int p = idx; p < 63 * 401; p += stride) {
        int c = p / 401, x = p - c * 401;
        float a = 0.f;
        #pragma unroll
        for (int j = 0; j < 25; ++j)
            a += Wobs[c * 25 + j] * ws[WS_OBSB + j * 401 + x];
        ws[WS_HOBS + p] = a;
    }
    unsigned short* Be = (unsigned short*)(ws + WS_BE);
    for (int p = idx; p < 64 * 2048; p += stride) {
        int c = p >> 11, k = p & 2047;
        float v = (c < 63 && k < E_NO) ? Ce[(size_t)(c + 1) * E_NO + k] : 0.f;
        Be[p] = f2bf(v);
    }
    unsigned short* Bi = (unsigned short*)(ws + WS_BI);
    for (int p = idx; p < 64 * 512; p += stride) {
        int c = p >> 9, k = p & 511;
        float v = (c < 63 && k < I_NO) ? Ci[(size_t)(c + 1) * I_NO + k] : 0.f;
        Bi[p] = f2bf(v);
    }
}

// ---------------- K2: bf16 MFMA GEMM, 64t x 64c tile, BK=64, split-K ---------
// grid (782, 4): y<3 -> E chunk y (K 704 each over 2048-pad); y==3 -> I (512).
// BK=64: 256B per A-row per step (2x DRAM page locality), 12 load-instrs in
// flight per wave at the staging wait (2x bytes), half the barriers (E 11
// steps, I 8). A guarded to 0 for k>=K kills the finite B over-read at y=2.
#define LDA 72   // bf16 row stride in LDS (144 B)
__global__ __launch_bounds__(128, 4) void gemm_kernel(const float* __restrict__ S_e,
                                                      const float* __restrict__ S_i,
                                                      float* __restrict__ ws) {
    __shared__ unsigned int Asu[64 * 36];   // 64 rows x 72 bf16 = 9216 B
    __shared__ unsigned int Bsu[64 * 36];

    const int y = blockIdx.y;
    const bool isE = (y < 3);
    const float* S = isE ? S_e : S_i;
    const unsigned short* Bm = (const unsigned short*)(ws + (isE ? WS_BE : WS_BI));
    const int K     = isE ? E_NO : I_NO;
    const int Kpad  = isE ? 2048 : 512;
    const int kb    = isE ? y * 704 : 0;
    const int nst   = isE ? 11 : 8;
    float* outp = ws + (isE ? (WS_PE0 + (size_t)y * PBSZ) : WS_PI);

    const int tid  = threadIdx.x;
    const int lane = tid & 63;
    const int w    = tid >> 6;            // wave 0..1
    const int t0   = blockIdx.x * 64;

    // A staging: 64 rows x 16 float4 per step; flat idx -> lanes 0..15 cover
    // one row's 256B contiguous (one wave instr = 4 rows x 256B).
    const int rA  = tid >> 4;       // base row 0..7 (g adds 8)
    const int c4A = tid & 15;       // float4 within row
    // B staging: 64 cols x 8 uint4 (64 bf16) per step.
    const int cB  = tid >> 3;       // base col 0..15 (g adds 16)
    const int sB  = tid & 7;        // uint4 within col

    float4 av[8];   // A rows rA, rA+8, ..., rA+56
    uint4  bv[4];   // B cols cB, cB+16, cB+32, cB+48

    auto pf = [&](int s) {
        const int kk = kb + 64 * s;
        const int kA = kk + 4 * c4A;
        #pragma unroll
        for (int g = 0; g < 8; ++g) {
            int t = t0 + rA + 8 * g;
            float4 v = {0.f, 0.f, 0.f, 0.f};
            if (t < TD && kA < K) v = *(const float4*)(S + (size_t)t * K + kA);
            av[g] = v;
        }
        #pragma unroll
        for (int g = 0; g < 4; ++g) {
            int col = cB + 16 * g;
            bv[g] = *(const uint4*)(Bm + (size_t)col * Kpad + kk + sB * 8);
        }
    };

    f32x4 acc[2][4] = {};   // [t-tile][c-tile], 16x16 each
    pf(0);
    for (int s = 0; s < nst; ++s) {
        __syncthreads();
        #pragma unroll
        for (int g = 0; g < 8; ++g) {
            int r = rA + 8 * g;
            uint2 w2 = {pack2(av[g].x, av[g].y), pack2(av[g].z, av[g].w)};
            *(uint2*)(Asu + r * 36 + c4A * 2) = w2;
        }
        #pragma unroll
        for (int g = 0; g < 4; ++g) {
            int col = cB + 16 * g;
            *(uint4*)(Bsu + col * 36 + sB * 4) = bv[g];
        }
        __syncthreads();
        if (s + 1 < nst) pf(s + 1);

        const unsigned short* As = (const unsigned short*)Asu;
        const unsigned short* Bs = (const unsigned short*)Bsu;
        const int quad8 = (lane >> 4) * 8;
        #pragma unroll
        for (int ks = 0; ks < 2; ++ks) {
            const int klocal = ks * 32 + quad8;
            s16x8 af[2], bf[4];
            #pragma unroll
            for (int ta = 0; ta < 2; ++ta) {
                int row = 32 * w + 16 * ta + (lane & 15);
                af[ta] = *(const s16x8*)(As + row * LDA + klocal);
            }
            #pragma unroll
            for (int cb = 0; cb < 4; ++cb) {
                int col = 16 * cb + (lane & 15);
                bf[cb] = *(const s16x8*)(Bs + col * LDA + klocal);
            }
            #pragma unroll
            for (int ta = 0; ta < 2; ++ta)
                #pragma unroll
                for (int cb = 0; cb < 4; ++cb)
                    acc[ta][cb] = __builtin_amdgcn_mfma_f32_16x16x32_bf16(af[ta], bf[cb], acc[ta][cb], 0, 0, 0);
        }
    }

    // epilogue: C/D layout col=lane&15, row=4*(lane>>4)+reg  (m89-verified)
    const int cl = lane & 15, rq = 4 * (lane >> 4);
    #pragma unroll
    for (int ta = 0; ta < 2; ++ta)
        #pragma unroll
        for (int cb = 0; cb < 4; ++cb) {
            int c = 16 * cb + cl;
            float* dst = outp + (size_t)c * TPAD + t0 + 32 * w + 16 * ta + rq;
            f32x4 v = acc[ta][cb];
            *(float4*)dst = make_float4(v.x, v.y, v.z, v.w);
        }
}

// ---------------- K3: FIR (sums 3 E partials + 1 I partial) -------------------
__device__ inline float4 ldg4(const float* s, int m) {
    return *(const float4*)(s + 4 * m + ((m >> 3) << 2));
}

__global__ __launch_bounds__(256) void fir_kernel(const float* __restrict__ pE0,
                                                  const float* __restrict__ pE1,
                                                  const float* __restrict__ pE2,
                                                  const float* __restrict__ pI0,
                                                  const float* __restrict__ Z,
                                                  const float* __restrict__ he,
                                                  const float* __restrict__ hi,
                                                  const float* __restrict__ ho,
                                                  const float* __restrict__ Theta,
                                                  float* __restrict__ L0T) {
    __shared__ __align__(16) float sE[1392];
    __shared__ __align__(16) float sI[1392];
    __shared__ __align__(16) float zs[1616];
    __shared__ __align__(16) float heS[200];
    __shared__ __align__(16) float hiS[200];
    __shared__ __align__(16) float hoS[404];

    const int c   = blockIdx.y;
    const int t0  = blockIdx.x * 1024;
    const int tid = threadIdx.x;
    const int base = t0 - 203;

    for (int w = tid; w < 1228; w += 256) {
        int t = base + w;
        bool ok = (t >= 0 && t < TD);
        size_t idx = (size_t)c * TPAD + t;
        float ve = 0.f, vi = 0.f;
        if (ok) {
            ve = pE0[idx] + pE1[idx] + pE2[idx];
            vi = pI0[idx];
        }
        sE[PADW(w)] = ve;
        sI[PADW(w)] = vi;
    }
    for (int w = tid; w < 1428; w += 256) {
        int t = base + w;
        zs[PADW(w)] = (t >= 0 && t < TD) ? Z[t] : 0.f;
    }
    for (int d = tid; d < 200; d += 256) { heS[d] = he[c * 200 + d]; hiS[d] = hi[c * 200 + d]; }
    for (int d = tid; d < 401; d += 256) hoS[d] = ho[c * 401 + d];
    __syncthreads();

    const float th = Theta[c];
    float acc[4] = {th, th, th, th};

    {
        float4 eLo = ldg4(sE, tid + 50), eHi = ldg4(sE, tid + 51);
        float4 iLo = ldg4(sI, tid + 50), iHi = ldg4(sI, tid + 51);
        for (int dg = 0; dg < 50; ++dg) {
            const float4 h_e = *(const float4*)(heS + 4 * dg);
            const float4 h_i = *(const float4*)(hiS + 4 * dg);
            const float ew[8] = {eLo.x, eLo.y, eLo.z, eLo.w, eHi.x, eHi.y, eHi.z, eHi.w};
            const float iw[8] = {iLo.x, iLo.y, iLo.z, iLo.w, iHi.x, iHi.y, iHi.z, iHi.w};
            const float heq[4] = {h_e.x, h_e.y, h_e.z, h_e.w};
            const float hiq[4] = {h_i.x, h_i.y, h_i.z, h_i.w};
            #pragma unroll
            for (int q = 0; q < 4; ++q)
                #pragma unroll
                for (int r = 0; r < 4; ++r) {
                    const int o = 3 + r - q;
                    acc[r] += ew[o] * heq[q] + iw[o] * hiq[q];
                }
            eHi = eLo; iHi = iLo;
            if (dg < 49) { eLo = ldg4(sE, tid + 49 - dg); iLo = ldg4(sI, tid + 49 - dg); }
        }
    }
    {
        float4 zLo = ldg4(zs, tid + 100), zHi = ldg4(zs, tid + 101);
        for (int dg = 0; dg < 100; ++dg) {
            const float4 h_o = *(const float4*)(hoS + 4 * dg);
            const float zw[8] = {zLo.x, zLo.y, zLo.z, zLo.w, zHi.x, zHi.y, zHi.z, zHi.w};
            const float hoq[4] = {h_o.x, h_o.y, h_o.z, h_o.w};
            #pragma unroll
            for (int q = 0; q < 4; ++q)
                #pragma unroll
                for (int r = 0; r < 4; ++r) {
                    const int o = 3 + r - q;
                    acc[r] += zw[o] * hoq[q];
                }
            zHi = zLo;
            if (dg < 99) zLo = ldg4(zs, tid + 99 - dg);
        }
        const float h400 = hoS[400];
        #pragma unroll
        for (int r = 0; r < 4; ++r) {
            int w = 4 * tid + 3 + r;
            acc[r] += zs[PADW(w)] * h400;
        }
    }

    const int tb = t0 + 4 * tid;
    if (tb + 3 < TD) {
        float4 v = {acc[0], acc[1], acc[2], acc[3]};
        *(float4*)(L0T + (size_t)c * TPAD + tb) = v;
    } else {
        #pragma unroll
        for (int r = 0; r < 4; ++r)
            if (tb + r < TD) L0T[(size_t)c * TPAD + tb + r] = acc[r];
    }
}

// ---------------- K4: transpose + Gumbel softmax + sigmoid --------------------
__global__ __launch_bounds__(256) void out_kernel(const float* __restrict__ L0T,
                                                  const float* __restrict__ u,
                                                  const float* __restrict__ temp_p,
                                                  float* __restrict__ out) {
    __shared__ float tile[63 * 65];
    const int t0 = blockIdx.x * 64;
    const int tid = threadIdx.x;

    for (int l = tid; l < 1008; l += 256) {
        int cc = l >> 4;
        int jg = (l & 15) << 2;
        float4 v = *(const float4*)(L0T + (size_t)cc * TPAD + t0 + jg);
        tile[cc * 65 + jg + 0] = v.x;
        tile[cc * 65 + jg + 1] = v.y;
        tile[cc * 65 + jg + 2] = v.z;
        tile[cc * 65 + jg + 3] = v.w;
    }
    __syncthreads();

    const float inv_temp = 1.f / (*temp_p);
    for (int l = tid; l < 4032; l += 256) {
        int tl = l / 63;
        int cc = l - tl * 63;
        int t = t0 + tl;
        if (t < TD) {
            float L0 = tile[cc * 65 + tl];
            float2 uv = *(const float2*)(u + 2 * ((size_t)t * 63 + cc));
            float g0 = -logf(-logf(uv.x + EPSF) + EPSF);
            float g1 = -logf(-logf(uv.y + EPSF) + EPSF);
            float zh = 1.f / (1.f + expf(-((L0 + g0 - g1) * inv_temp)));
            float sg = 1.f / (1.f + expf(-L0));
            out[(size_t)t * 63 + cc] = zh;
            out[3150000 + (size_t)t * 63 + cc] = sg;
        }
    }
}

extern "C" void kernel_launch(void* const* d_in, const int* in_sizes, int n_in,
                              void* d_out, int out_size, void* d_ws, size_t ws_size,
                              hipStream_t stream) {
    (void)in_sizes; (void)n_in; (void)out_size; (void)ws_size;
    const float* S_e   = (const float*)d_in[0];
    const float* S_i   = (const float*)d_in[1];
    const float* Z     = (const float*)d_in[2];
    const float* temp  = (const float*)d_in[3];
    const float* u     = (const float*)d_in[4];
    const float* Ce    = (const float*)d_in[5];
    const float* Ci    = (const float*)d_in[6];
    const float* Wsyn  = (const float*)d_in[7];
    const float* Wobs  = (const float*)d_in[8];
    const float* Theta = (const float*)d_in[9];
    float* out = (float*)d_out;
    float* ws  = (float*)d_ws;

    hipLaunchKernelGGL(basis_kernel, dim3(50), dim3(256), 0, stream, ws);
    hipLaunchKernelGGL(prep_kernel, dim3(256), dim3(256), 0, stream, Wsyn, Wobs, Ce, Ci, ws);
    hipLaunchKernelGGL(gemm_kernel, dim3(782, 4), dim3(128), 0, stream, S_e, S_i, ws);
    hipLaunchKernelGGL(fir_kernel, dim3(49, 63), dim3(256), 0, stream,
                       ws + WS_PE0, ws + WS_PE0 + PBSZ, ws + WS_PE0 + 2 * (size_t)PBSZ,
                       ws + WS_PI, Z,
                       ws + WS_HE, ws + WS_HI, ws + WS_HOBS, Theta, ws + WS_L0T);
    hipLaunchKernelGGL(out_kernel, dim3(782), dim3(256), 0, stream, ws + WS_L0T, u, temp, out);
}

// Round 4
// 880.586 us; speedup vs baseline: 1.1573x; 1.0224x over previous
//
#include <hip/hip_runtime.h>
#include <math.h>

#define T_NO   200
#define C_NO   63
#define E_NO   2000
#define I_NO   500
#define TD     50000
#define TPAD   50048
#define EPSF   1e-8f

typedef float f32x4 __attribute__((ext_vector_type(4)));
typedef short s16x8 __attribute__((ext_vector_type(8)));

// ws layout (float offsets)
#define WS_HE    0              // 63*200
#define WS_HI    12600          // 63*200
#define WS_HOBS  25200          // 63*401 -> 50463
#define WS_COSB  50464          // 13*200 -> 53064
#define WS_OBSB  53064          // 25*401 -> 63089
#define WS_BE    63104          // bf16 64*2048 (65536 floats) -> 128640
#define WS_BI    128640         // bf16 64*512  (16384 floats) -> 145024
#define WS_PE0   145024         // 2 E partials, 64*TPAD each
#define PBSZ     3203072
#define WS_PI    9754240        // 1 I partial
#define WS_L0T   12957312       // 63*TPAD -> 16110336 floats (~61.5 MB)

// padded LDS map for FIR: +4 words every 32 data words
#define PADW(w) ((w) + (((w) >> 5) << 2))

__device__ inline unsigned short f2bf(float x) {   // RNE fp32->bf16
    unsigned u = __float_as_uint(x);
    return (unsigned short)((u + 0x7FFFu + ((u >> 16) & 1u)) >> 16);
}
__device__ inline unsigned pack2(float lo, float hi) {
    return (unsigned)f2bf(lo) | ((unsigned)f2bf(hi) << 16);
}

// ---------------- K0: raised-cosine bases (double math ONCE per basis point) --
__global__ void basis_kernel(float* __restrict__ ws) {
    const double PI = 3.14159265358979323846;
    int idx = blockIdx.x * blockDim.x + threadIdx.x;
    int stride = gridDim.x * blockDim.x;
    for (int p = idx; p < 13 * 200; p += stride) {
        int i = p / 200, t = p - i * 200;
        double raw = 5.0 * log((double)t + 1.0 + 1e-8);
        double phi = 0.5 * PI * (double)i;
        float b = (raw >= phi - PI && raw <= phi + PI) ? (float)(0.5 * cos(raw - phi) + 0.5) : 0.f;
        ws[WS_COSB + p] = b;
    }
    for (int p = idx; p < 25 * 401; p += stride) {
        int j = p / 401, x = p - j * 401;
        int i = (j + 1) >> 1;
        double raw = 5.0 * log(fabs((double)(x - 200)) + 1.0 + 1e-8);
        double phi = 0.5 * PI * (double)i;
        float b = (raw >= phi - PI && raw <= phi + PI) ? (float)(0.5 * cos(raw - phi) + 0.5) : 0.f;
        if (j > 0) {
            if (j & 1) { if (x < 200) b = 0.f; }   // row 2i-1: keep x>=200
            else       { if (x > 200) b = 0.f; }   // row 2i:   keep x<=200
        }
        ws[WS_OBSB + p] = b;
    }
}

// ---------------- K1: weight filters + pre-convert B matrices to bf16 --------
__global__ void prep_kernel(const float* __restrict__ Wsyn, const float* __restrict__ Wobs,
                            const float* __restrict__ Ce, const float* __restrict__ Ci,
                            float* __restrict__ ws) {
    int idx = blockIdx.x * blockDim.x + threadIdx.x;
    int stride = gridDim.x * blockDim.x;
    for (int p = idx; p < 63 * 200; p += stride) {
        int c = p / 200, t = p - c * 200;
        float ae = 0.f, ai = 0.f;
        #pragma unroll
        for (int b = 0; b < 13; ++b) {
            float bv = ws[WS_COSB + b * 200 + t];
            ae += Wsyn[(c * 13 + b) * 2 + 0] * bv;
            ai += Wsyn[(c * 13 + b) * 2 + 1] * bv;
        }
        ws[WS_HE + p] = ae;
        ws[WS_HI + p] = ai;
    }
    for (int p = idx; p < 63 * 401; p += stride) {
        int c = p / 401, x = p - c * 401;
        float a = 0.f;
        #pragma unroll
        for (int j = 0; j < 25; ++j)
            a += Wobs[c * 25 + j] * ws[WS_OBSB + j * 401 + x];
        ws[WS_HOBS + p] = a;
    }
    unsigned short* Be = (unsigned short*)(ws + WS_BE);
    for (int p = idx; p < 64 * 2048; p += stride) {
        int c = p >> 11, k = p & 2047;
        float v = (c < 63 && k < E_NO) ? Ce[(size_t)(c + 1) * E_NO + k] : 0.f;
        Be[p] = f2bf(v);
    }
    unsigned short* Bi = (unsigned short*)(ws + WS_BI);
    for (int p = idx; p < 64 * 512; p += stride) {
        int c = p >> 9, k = p & 511;
        float v = (c < 63 && k < I_NO) ? Ci[(size_t)(c + 1) * I_NO + k] : 0.f;
        Bi[p] = f2bf(v);
    }
}

// ---------------- K2: bf16 MFMA GEMM, 64t x 64c tile, BK=64 ------------------
// grid (782, 3): y<2 -> E chunk y (K=1024 each); y==2 -> I (512).
// LDS DOUBLE-BUFFER, one barrier per step (T3-minimal 2-phase): loads for
// step s+1 stay in flight across compute(s); ds_write targets the idle
// buffer so no second barrier. Epilogue bounces C through LDS so each
// partial column is stored as contiguous 256B full lines (kills the 3.7x
// WRITE_SIZE amplification seen in R1-R3).
#define LDA 72   // bf16 row stride in LDS (144 B)
__global__ __launch_bounds__(128, 2) void gemm_kernel(const float* __restrict__ S_e,
                                                      const float* __restrict__ S_i,
                                                      float* __restrict__ ws) {
    __shared__ unsigned int Asu[2][64 * 36];   // 9216 B each
    __shared__ unsigned int Bsu[2][64 * 36];

    const int y = blockIdx.y;
    const bool isE = (y < 2);
    const float* S = isE ? S_e : S_i;
    const unsigned short* Bm = (const unsigned short*)(ws + (isE ? WS_BE : WS_BI));
    const int K     = isE ? E_NO : I_NO;
    const int Kpad  = isE ? 2048 : 512;
    const int kb    = isE ? y * 1024 : 0;
    const int nst   = isE ? 16 : 8;
    float* outp = ws + (isE ? (WS_PE0 + (size_t)y * PBSZ) : WS_PI);

    const int tid  = threadIdx.x;
    const int lane = tid & 63;
    const int w    = tid >> 6;            // wave 0..1
    const int t0   = blockIdx.x * 64;

    // A staging: 64 rows x 16 float4 per step; lanes 0..15 cover one row's
    // 256B contiguous.
    const int rA  = tid >> 4;       // base row 0..7 (g adds 8)
    const int c4A = tid & 15;       // float4 within row
    // B staging: 64 cols x 8 uint4 (64 bf16) per step.
    const int cB  = tid >> 3;       // base col 0..15 (g adds 16)
    const int sB  = tid & 7;        // uint4 within col

    float4 av[8];   // A rows rA, rA+8, ..., rA+56
    uint4  bv[4];   // B cols cB, cB+16, cB+32, cB+48

    auto pf = [&](int s) {
        const int kk = kb + 64 * s;
        const int kA = kk + 4 * c4A;
        #pragma unroll
        for (int g = 0; g < 8; ++g) {
            int t = t0 + rA + 8 * g;
            float4 v = {0.f, 0.f, 0.f, 0.f};
            if (t < TD && kA < K) v = *(const float4*)(S + (size_t)t * K + kA);
            av[g] = v;
        }
        #pragma unroll
        for (int g = 0; g < 4; ++g) {
            int col = cB + 16 * g;
            bv[g] = *(const uint4*)(Bm + (size_t)col * Kpad + kk + sB * 8);
        }
    };

    auto wr = [&](int b) {
        #pragma unroll
        for (int g = 0; g < 8; ++g) {
            int r = rA + 8 * g;
            uint2 w2 = {pack2(av[g].x, av[g].y), pack2(av[g].z, av[g].w)};
            *(uint2*)(&Asu[b][r * 36 + c4A * 2]) = w2;
        }
        #pragma unroll
        for (int g = 0; g < 4; ++g) {
            int col = cB + 16 * g;
            *(uint4*)(&Bsu[b][col * 36 + sB * 4]) = bv[g];
        }
    };

    f32x4 acc[2][4] = {};   // [t-tile][c-tile], 16x16 each

    auto cmp = [&](int b) {
        const unsigned short* As = (const unsigned short*)Asu[b];
        const unsigned short* Bs = (const unsigned short*)Bsu[b];
        const int quad8 = (lane >> 4) * 8;
        #pragma unroll
        for (int ks = 0; ks < 2; ++ks) {
            const int klocal = ks * 32 + quad8;
            s16x8 af[2], bf[4];
            #pragma unroll
            for (int ta = 0; ta < 2; ++ta) {
                int row = 32 * w + 16 * ta + (lane & 15);
                af[ta] = *(const s16x8*)(As + row * LDA + klocal);
            }
            #pragma unroll
            for (int cb = 0; cb < 4; ++cb) {
                int col = 16 * cb + (lane & 15);
                bf[cb] = *(const s16x8*)(Bs + col * LDA + klocal);
            }
            #pragma unroll
            for (int ta = 0; ta < 2; ++ta)
                #pragma unroll
                for (int cb = 0; cb < 4; ++cb)
                    acc[ta][cb] = __builtin_amdgcn_mfma_f32_16x16x32_bf16(af[ta], bf[cb], acc[ta][cb], 0, 0, 0);
        }
    };

    // prologue: buf0 filled, loads for step 1 in flight
    pf(0);
    wr(0);
    pf(1);
    __syncthreads();

    for (int s = 0; s < nst; ++s) {
        cmp(s & 1);
        if (s + 1 < nst) {
            wr((s + 1) & 1);          // waits only on pf(s+1) regs
            if (s + 2 < nst) pf(s + 2);
        }
        __syncthreads();
    }

    // epilogue: stage C in LDS, then full-line contiguous stores.
    // C/D layout col=lane&15, row=4*(lane>>4)+reg (m89-verified)
    float* tile = (float*)Asu;        // 64 cols x 68 floats = 17408 B
    const int cl = lane & 15, rq = 4 * (lane >> 4);
    #pragma unroll
    for (int ta = 0; ta < 2; ++ta)
        #pragma unroll
        for (int cb = 0; cb < 4; ++cb) {
            int c = 16 * cb + cl;
            int r = 32 * w + 16 * ta + rq;
            f32x4 v = acc[ta][cb];
            tile[c * 68 + r + 0] = v.x;
            tile[c * 68 + r + 1] = v.y;
            tile[c * 68 + r + 2] = v.z;
            tile[c * 68 + r + 3] = v.w;
        }
    __syncthreads();
    #pragma unroll
    for (int g = 0; g < 8; ++g) {
        int idx = g * 128 + tid;          // 1024 float4s: 64 cols x 16
        int c = idx >> 4, r4 = (idx & 15) << 2;
        float4 v = *(const float4*)(tile + c * 68 + r4);
        *(float4*)(outp + (size_t)c * TPAD + t0 + r4) = v;
    }
}

// ---------------- K3: FIR (sums 2 E partials + 1 I partial) -------------------
__device__ inline float4 ldg4(const float* s, int m) {
    return *(const float4*)(s + 4 * m + ((m >> 3) << 2));
}

__global__ __launch_bounds__(256) void fir_kernel(const float* __restrict__ pE0,
                                                  const float* __restrict__ pE1,
                                                  const float* __restrict__ pI0,
                                                  const float* __restrict__ Z,
                                                  const float* __restrict__ he,
                                                  const float* __restrict__ hi,
                                                  const float* __restrict__ ho,
                                                  const float* __restrict__ Theta,
                                                  float* __restrict__ L0T) {
    __shared__ __align__(16) float sE[1392];
    __shared__ __align__(16) float sI[1392];
    __shared__ __align__(16) float zs[1616];
    __shared__ __align__(16) float heS[200];
    __shared__ __align__(16) float hiS[200];
    __shared__ __align__(16) float hoS[404];

    const int c   = blockIdx.y;
    const int t0  = blockIdx.x * 1024;
    const int tid = threadIdx.x;
    const int base = t0 - 203;

    for (int w = tid; w < 1228; w += 256) {
        int t = base + w;
        bool ok = (t >= 0 && t < TD);
        size_t idx = (size_t)c * TPAD + t;
        float ve = 0.f, vi = 0.f;
        if (ok) {
            ve = pE0[idx] + pE1[idx];
            vi = pI0[idx];
        }
        sE[PADW(w)] = ve;
        sI[PADW(w)] = vi;
    }
    for (int w = tid; w < 1428; w += 256) {
        int t = base + w;
        zs[PADW(w)] = (t >= 0 && t < TD) ? Z[t] : 0.f;
    }
    for (int d = tid; d < 200; d += 256) { heS[d] = he[c * 200 + d]; hiS[d] = hi[c * 200 + d]; }
    for (int d = tid; d < 401; d += 256) hoS[d] = ho[c * 401 + d];
    __syncthreads();

    const float th = Theta[c];
    float acc[4] = {th, th, th, th};

    {
        float4 eLo = ldg4(sE, tid + 50), eHi = ldg4(sE, tid + 51);
        float4 iLo = ldg4(sI, tid + 50), iHi = ldg4(sI, tid + 51);
        for (int dg = 0; dg < 50; ++dg) {
            const float4 h_e = *(const float4*)(heS + 4 * dg);
            const float4 h_i = *(const float4*)(hiS + 4 * dg);
            const float ew[8] = {eLo.x, eLo.y, eLo.z, eLo.w, eHi.x, eHi.y, eHi.z, eHi.w};
            const float iw[8] = {iLo.x, iLo.y, iLo.z, iLo.w, iHi.x, iHi.y, iHi.z, iHi.w};
            const float heq[4] = {h_e.x, h_e.y, h_e.z, h_e.w};
            const float hiq[4] = {h_i.x, h_i.y, h_i.z, h_i.w};
            #pragma unroll
            for (int q = 0; q < 4; ++q)
                #pragma unroll
                for (int r = 0; r < 4; ++r) {
                    const int o = 3 + r - q;
                    acc[r] += ew[o] * heq[q] + iw[o] * hiq[q];
                }
            eHi = eLo; iHi = iLo;
            if (dg < 49) { eLo = ldg4(sE, tid + 49 - dg); iLo = ldg4(sI, tid + 49 - dg); }
        }
    }
    {
        float4 zLo = ldg4(zs, tid + 100), zHi = ldg4(zs, tid + 101);
        for (int dg = 0; dg < 100; ++dg) {
            const float4 h_o = *(const float4*)(hoS + 4 * dg);
            const float zw[8] = {zLo.x, zLo.y, zLo.z, zLo.w, zHi.x, zHi.y, zHi.z, zHi.w};
            const float hoq[4] = {h_o.x, h_o.y, h_o.z, h_o.w};
            #pragma unroll
            for (int q = 0; q < 4; ++q)
                #pragma unroll
                for (int r = 0; r < 4; ++r) {
                    const int o = 3 + r - q;
                    acc[r] += zw[o] * hoq[q];
                }
            zHi = zLo;
            if (dg < 99) zLo = ldg4(zs, tid + 99 - dg);
        }
        const float h400 = hoS[400];
        #pragma unroll
        for (int r = 0; r < 4; ++r) {
            int w = 4 * tid + 3 + r;
            acc[r] += zs[PADW(w)] * h400;
        }
    }

    const int tb = t0 + 4 * tid;
    if (tb + 3 < TD) {
        float4 v = {acc[0], acc[1], acc[2], acc[3]};
        *(float4*)(L0T + (size_t)c * TPAD + tb) = v;
    } else {
        #pragma unroll
        for (int r = 0; r < 4; ++r)
            if (tb + r < TD) L0T[(size_t)c * TPAD + tb + r] = acc[r];
    }
}

// ---------------- K4: transpose + Gumbel softmax + sigmoid --------------------
__global__ __launch_bounds__(256) void out_kernel(const float* __restrict__ L0T,
                                                  const float* __restrict__ u,
                                                  const float* __restrict__ temp_p,
                                                  float* __restrict__ out) {
    __shared__ float tile[63 * 65];
    const int t0 = blockIdx.x * 64;
    const int tid = threadIdx.x;

    for (int l = tid; l < 1008; l += 256) {
        int cc = l >> 4;
        int jg = (l & 15) << 2;
        float4 v = *(const float4*)(L0T + (size_t)cc * TPAD + t0 + jg);
        tile[cc * 65 + jg + 0] = v.x;
        tile[cc * 65 + jg + 1] = v.y;
        tile[cc * 65 + jg + 2] = v.z;
        tile[cc * 65 + jg + 3] = v.w;
    }
    __syncthreads();

    const float inv_temp = 1.f / (*temp_p);
    for (int l = tid; l < 4032; l += 256) {
        int tl = l / 63;
        int cc = l - tl * 63;
        int t = t0 + tl;
        if (t < TD) {
            float L0 = tile[cc * 65 + tl];
            float2 uv = *(const float2*)(u + 2 * ((size_t)t * 63 + cc));
            float g0 = -logf(-logf(uv.x + EPSF) + EPSF);
            float g1 = -logf(-logf(uv.y + EPSF) + EPSF);
            float zh = 1.f / (1.f + expf(-((L0 + g0 - g1) * inv_temp)));
            float sg = 1.f / (1.f + expf(-L0));
            out[(size_t)t * 63 + cc] = zh;
            out[3150000 + (size_t)t * 63 + cc] = sg;
        }
    }
}

extern "C" void kernel_launch(void* const* d_in, const int* in_sizes, int n_in,
                              void* d_out, int out_size, void* d_ws, size_t ws_size,
                              hipStream_t stream) {
    (void)in_sizes; (void)n_in; (void)out_size; (void)ws_size;
    const float* S_e   = (const float*)d_in[0];
    const float* S_i   = (const float*)d_in[1];
    const float* Z     = (const float*)d_in[2];
    const float* temp  = (const float*)d_in[3];
    const float* u     = (const float*)d_in[4];
    const float* Ce    = (const float*)d_in[5];
    const float* Ci    = (const float*)d_in[6];
    const float* Wsyn  = (const float*)d_in[7];
    const float* Wobs  = (const float*)d_in[8];
    const float* Theta = (const float*)d_in[9];
    float* out = (float*)d_out;
    float* ws  = (float*)d_ws;

    hipLaunchKernelGGL(basis_kernel, dim3(50), dim3(256), 0, stream, ws);
    hipLaunchKernelGGL(prep_kernel, dim3(256), dim3(256), 0, stream, Wsyn, Wobs, Ce, Ci, ws);
    hipLaunchKernelGGL(gemm_kernel, dim3(782, 3), dim3(128), 0, stream, S_e, S_i, ws);
    hipLaunchKernelGGL(fir_kernel, dim3(49, 63), dim3(256), 0, stream,
                       ws + WS_PE0, ws + WS_PE0 + PBSZ,
                       ws + WS_PI, Z,
                       ws + WS_HE, ws + WS_HI, ws + WS_HOBS, Theta, ws + WS_L0T);
    hipLaunchKernelGGL(out_kernel, dim3(782), dim3(256), 0, stream, ws + WS_L0T, u, temp, out);
}